// Round 15
// baseline (231.384 us; speedup 1.0000x reference)
//
#include <hip/hip_runtime.h>

// Shapes (fixed per reference): B=2, L=2048, D=1024, H=16, Dh=64
typedef __bf16 bf16;
typedef __attribute__((ext_vector_type(8))) __bf16 bf16x8;
typedef __attribute__((ext_vector_type(4))) __bf16 bf16x4;
typedef __attribute__((ext_vector_type(4))) float f32x4;

__device__ inline bf16 f2bf(float f) {
  unsigned u = __builtin_bit_cast(unsigned, f);
  u += 0x7fff + ((u >> 16) & 1);  // RNE
  unsigned short h = (unsigned short)(u >> 16);
  return __builtin_bit_cast(bf16, h);
}

__device__ inline void gl_lds16(const bf16* g, bf16* l) {
  __builtin_amdgcn_global_load_lds(
      (const __attribute__((address_space(1))) void*)g,
      (__attribute__((address_space(3))) void*)l, 16, 0, 0);
}

// ---------------- fp32 -> bf16 conversion + fused RoPE table --------------
__global__ __launch_bounds__(256) void cvt_kernel(
    const float* __restrict__ x, const float* __restrict__ wq,
    const float* __restrict__ wk, const float* __restrict__ wv,
    const float* __restrict__ wo, bf16* __restrict__ dst,
    const int* __restrict__ pos, float* __restrict__ tab) {
  if (blockIdx.x >= 8192) {
    int gid = (blockIdx.x - 8192) * 256 + threadIdx.x;  // 65536 items
    int tok = gid >> 5, j = gid & 31;
    float freq = exp2f(-(float)(2 * j) * 0.20762051f);
    float angle = (float)pos[tok] * freq;
    float sn, cs;
    sincosf(angle, &sn, &cs);
    *(float2*)(tab + tok * 64 + j * 2) = make_float2(cs, sn);
    return;
  }
  int idx = (blockIdx.x * 256 + threadIdx.x) * 4;
  const float* src;
  if (idx < 4194304) {
    src = x + idx;
  } else {
    int j = idx - 4194304;
    int w = j >> 20;  // uniform per block
    const float* sw = (w == 0) ? wq : (w == 1) ? wk : (w == 2) ? wv : wo;
    src = sw + (j & 1048575);
  }
  float4 f = *(const float4*)src;
  bf16x4 o = {f2bf(f.x), f2bf(f.y), f2bf(f.z), f2bf(f.w)};
  *(bf16x4*)(dst + idx) = o;
}

// ---------------- QKV projection GEMM + RoPE epilogue ---------------------
// R17: A-operand DIRECT FROM GLOBAL (reg double-buffered afA/afB two-phase,
// prefetch kt+1 before compute kt); only B staged in LDS (dbuf 2x8KB).
// Rationale: R16 counters put the kernel at the LDS-total-BW bound
// (3 blk/CU x (16KB DMA-write + 32KB read) = 144KB/step = 1125cyc vs
// measured ~1400, MFMA only ~230). A-rows are wave-private -> staging them
// through LDS was pure traffic; direct loads are 16x64B segments, L1-served
// (2 waves share rows; each 128B line spans 2 k-steps). LDS traffic/step
// 48KB -> 24KB. B swizzle/pipeline unchanged from R16 (verified).
__global__ __launch_bounds__(256) void gemm_qkv_kernel(
    const bf16* __restrict__ xb, const bf16* __restrict__ wb,
    const float* __restrict__ tab,
    bf16* __restrict__ Qb, bf16* __restrict__ Kb, bf16* __restrict__ Vtb) {
  __shared__ __align__(16) bf16 smem[8704];  // B0[4096]|B1[4096]; epi T[64*136]
  int tid = threadIdx.x;
  int lane = tid & 63, w = tid >> 6;
  int l15 = lane & 15, quad = lane >> 4;
  int bid = blockIdx.x;
  int xcd = bid & 7, j = bid >> 3;       // XCD round-robin; j in [0,96)
  int by = (xcd & 3) * 8 + (j & 7);      // 32 M-tiles, 8 per XCD row-group
  int bx = (xcd >> 2) * 12 + (j >> 3);   // 24 N-tiles, 12 per XCD col-group
  int mb = by * 128, nb = bx * 128;
  int mq = (w & 1) * 64, nq = (w >> 1) * 64;
  int rq = lane >> 2;                               // row-in-16 for staging
  int gsrc = (lane & 3) ^ (rq & 3) ^ (lane >> 4);   // pre-swizzled src granule
  const bf16* bgp0 = wb + (size_t)(nb + w * 32 + rq) * 1024 + gsrc * 8;
  const bf16* bgp1 = bgp0 + 16 * 1024;
  const bf16* agp = xb + (size_t)(mb + mq + l15) * 1024 + quad * 8;
  f32x4 acc[4][4];
#pragma unroll
  for (int i = 0; i < 4; ++i)
#pragma unroll
    for (int j2 = 0; j2 < 4; ++j2)
      for (int r = 0; r < 4; ++r) acc[i][j2][r] = 0.f;
  bf16x8 afA[4], afB[4];
  // prologue: stage B step 0 into buf0; load A step 0 into afA
  gl_lds16(bgp0, smem + w * 1024);
  gl_lds16(bgp1, smem + w * 1024 + 512);
  bgp0 += 32; bgp1 += 32;
#pragma unroll
  for (int mt = 0; mt < 4; ++mt)
    afA[mt] = *(const bf16x8*)(agp + mt * 16384);
  __syncthreads();
  int rg = quad ^ (l15 & 3) ^ (l15 >> 2);  // read granule (matches gsrc)

#define QKV_STEP(AFC, AFN)                                                    \
  {                                                                           \
    bf16* Bb = smem + (kt & 1) * 4096;                                        \
    if (kt < 31) { /* stage B(kt+1) + prefetch A(kt+1) before compute */      \
      bf16* Bn = smem + ((kt & 1) ^ 1) * 4096;                                \
      gl_lds16(bgp0, Bn + w * 1024);                                          \
      gl_lds16(bgp1, Bn + w * 1024 + 512);                                    \
      bgp0 += 32; bgp1 += 32;                                                 \
      _Pragma("unroll") for (int mt = 0; mt < 4; ++mt)                        \
          AFN[mt] = *(const bf16x8*)(agp + 32 + mt * 16384);                  \
      agp += 32;                                                              \
    }                                                                         \
    bf16x8 bfr[4];                                                            \
    _Pragma("unroll") for (int nt = 0; nt < 4; ++nt)                          \
        bfr[nt] = *(const bf16x8*)(Bb + (nq + nt * 16 + l15) * 32 + rg * 8);  \
    _Pragma("unroll") for (int mt = 0; mt < 4; ++mt)                          \
        _Pragma("unroll") for (int nt = 0; nt < 4; ++nt)                      \
            acc[mt][nt] = __builtin_amdgcn_mfma_f32_16x16x32_bf16(            \
                AFC[mt], bfr[nt], acc[mt][nt], 0, 0, 0);                      \
    __syncthreads();                                                          \
  }

  int kt = 0;
  for (;;) {
    QKV_STEP(afA, afB);
    ++kt;
    if (kt >= 32) break;
    QKV_STEP(afB, afA);
    ++kt;
    if (kt >= 32) break;
  }
#undef QKV_STEP

  int b = mb >> 11;        // block-uniform batch
  int mtok = mb & 2047;    // block-uniform token base
  if (bx < 16) {
    // ---- Q or K tile: RoPE epilogue (C col=l15 -> e, row=quad*4+r -> tok)
    bf16* dst = (bx < 8) ? Qb : Kb;
#pragma unroll
    for (int nt = 0; nt < 4; ++nt) {
      int e = nb + nq + nt * 16 + l15;
      int d = e & 63;
      int h = (e & 1023) >> 6;
      int tbase = d & ~1;
#pragma unroll
      for (int mt = 0; mt < 4; ++mt) {
#pragma unroll
        for (int r = 0; r < 4; ++r) {
          int ltok = mtok + mq + mt * 16 + quad * 4 + r;
          float val = acc[mt][nt][r];
          float p = __shfl_xor(val, 1);
          float2 cs2 = *(const float2*)(tab + ltok * 64 + tbase);
          float outv = (e & 1) ? (p * cs2.y + val * cs2.x) : (val * cs2.x - p * cs2.y);
          dst[(size_t)(((b << 4) + h) * 2048 + ltok) * 64 + d] = f2bf(outv);
        }
      }
    }
  } else {
    // ---- V tile: transpose via LDS (smem dead after K-loop), coalesced Vt
    bf16* T = smem;  // [64][136] bf16 = 17408 B
    for (int h2 = 0; h2 < 2; ++h2) {
      if ((w >> 1) == h2) {  // waves owning cols [h2*64, h2*64+64)
#pragma unroll
        for (int nt = 0; nt < 4; ++nt)
#pragma unroll
          for (int mt = 0; mt < 4; ++mt) {
            bf16x4 tv = {f2bf(acc[mt][nt][0]), f2bf(acc[mt][nt][1]),
                         f2bf(acc[mt][nt][2]), f2bf(acc[mt][nt][3])};
            *(bf16x4*)&T[(nt * 16 + l15) * 136 + mq + mt * 16 + quad * 4] = tv;
          }
      }
      __syncthreads();
      int row = tid >> 2, cs = (tid & 3) * 32;
      int e = nb + h2 * 64 + row;
      int d = e & 63, hh = (e & 1023) >> 6;
      bf16* vdst = Vtb + ((size_t)((b << 4) + hh) * 64 + d) * 2048 + mtok + cs;
#pragma unroll
      for (int j3 = 0; j3 < 4; ++j3)
        *(bf16x8*)(vdst + j3 * 8) = *(const bf16x8*)&T[row * 136 + cs + j3 * 8];
      __syncthreads();
    }
  }
}

// ---------------- causal flash attention v11 (R16, frozen) -----------------
#define SCALE_L2E 0.18033688f  // 0.125 * log2(e)
__global__ __launch_bounds__(256) void attn_kernel(
    const bf16* __restrict__ Qb, const bf16* __restrict__ Kb,
    const bf16* __restrict__ Vtb, bf16* __restrict__ Ob) {
  __shared__ __align__(16) bf16 Ks[64 * 64];
  __shared__ __align__(16) bf16 Vs[64 * 64];
  __shared__ __align__(16) bf16 pbuf[4][16 * 72];
  int tid = threadIdx.x;
  int lane = tid & 63, w = tid >> 6;
  int l15 = lane & 15, quad = lane >> 4;
  int bidx = blockIdx.x;
  int bh = bidx & 31;
  int qt = 31 - (bidx >> 5);  // LPT: longest q-tiles dispatch first
  int qbase = qt * 64;
  const bf16* Qp = Qb + (size_t)bh * 131072;
  const bf16* Kp = Kb + (size_t)bh * 131072;
  const bf16* Vp = Vtb + (size_t)bh * 131072;
  int r8 = lane >> 3;
  int gsw8 = (lane & 7) ^ r8;       // staging source granule swizzle
  int g0 = quad ^ (l15 & 7);        // read granule, k-chunk 0
  int g1 = (4 + quad) ^ (l15 & 7);  // read granule, k-chunk 1
  bf16x8 qf[2];
#pragma unroll
  for (int c = 0; c < 2; ++c)
    qf[c] = *(const bf16x8*)(Qp + (size_t)(qbase + w * 16 + l15) * 64 + c * 32 + quad * 8);
  f32x4 oacc[4];
#pragma unroll
  for (int dt = 0; dt < 4; ++dt)
    for (int r = 0; r < 4; ++r) oacc[dt][r] = 0.f;
  float lpart = 0.f;  // per-lane partial denominator
  int qmin_w = qbase + w * 16;
  int ntiles = qt + 1;

  {  // prologue: stage tile 0 via gl_lds
    const bf16* ksrc = Kp + (size_t)(w * 16 + r8) * 64 + gsw8 * 8;
    bf16* kdst = &Ks[(w * 16) * 64];
    gl_lds16(ksrc, kdst);
    gl_lds16(ksrc + 8 * 64, kdst + 8 * 64);
    const bf16* vsrc = Vp + (size_t)(w * 16 + r8) * 2048 + gsw8 * 8;
    bf16* vdst = &Vs[(w * 16) * 64];
    gl_lds16(vsrc, vdst);
    gl_lds16(vsrc + 8 * 2048, vdst + 8 * 64);
  }
  __syncthreads();

  for (int t = 0; t < ntiles; ++t) {
    int kb = t * 64;
    bool pf = (t + 1 < ntiles);  // wave-uniform
    bf16x8 rk0, rk1, rv0, rv1;
    if (pf) {  // issue prefetch for tile t+1; lands during compute below
      const bf16* ksrc = Kp + (size_t)(kb + 64 + w * 16 + r8) * 64 + gsw8 * 8;
      rk0 = *(const bf16x8*)ksrc;
      rk1 = *(const bf16x8*)(ksrc + 8 * 64);
      const bf16* vsrc = Vp + (size_t)(w * 16 + r8) * 2048 + kb + 64 + gsw8 * 8;
      rv0 = *(const bf16x8*)vsrc;
      rv1 = *(const bf16x8*)(vsrc + 8 * 2048);
    }
    {  // compute tile t
      bf16x8 kf[4][2], vf[4][2];
#pragma unroll
      for (int kt = 0; kt < 4; ++kt) {
        kf[kt][0] = *(const bf16x8*)(&Ks[(kt * 16 + l15) * 64 + g0 * 8]);
        kf[kt][1] = *(const bf16x8*)(&Ks[(kt * 16 + l15) * 64 + g1 * 8]);
      }
#pragma unroll
      for (int dt = 0; dt < 4; ++dt) {
        vf[dt][0] = *(const bf16x8*)(&Vs[(dt * 16 + l15) * 64 + g0 * 8]);
        vf[dt][1] = *(const bf16x8*)(&Vs[(dt * 16 + l15) * 64 + g1 * 8]);
      }
      int q = qmin_w + l15;
      f32x4 s[4];
#pragma unroll
      for (int kt = 0; kt < 4; ++kt) {
        for (int r = 0; r < 4; ++r) s[kt][r] = 0.f;
        s[kt] = __builtin_amdgcn_mfma_f32_16x16x32_bf16(kf[kt][0], qf[0], s[kt], 0, 0, 0);
        s[kt] = __builtin_amdgcn_mfma_f32_16x16x32_bf16(kf[kt][1], qf[1], s[kt], 0, 0, 0);
      }
      float pe[16];
      if (kb + 63 > qmin_w) {  // diagonal: per-element mask (wave-uniform test)
#pragma unroll
        for (int kt = 0; kt < 4; ++kt)
#pragma unroll
          for (int r = 0; r < 4; ++r) {
            int key = kb + kt * 16 + quad * 4 + r;
            pe[kt * 4 + r] = (key <= q) ? exp2f(s[kt][r] * SCALE_L2E) : 0.f;
          }
      } else {
#pragma unroll
        for (int kt = 0; kt < 4; ++kt)
#pragma unroll
          for (int r = 0; r < 4; ++r) pe[kt * 4 + r] = exp2f(s[kt][r] * SCALE_L2E);
      }
#pragma unroll
      for (int i = 0; i < 16; ++i) lpart += pe[i];
#pragma unroll
      for (int kt = 0; kt < 4; ++kt) {
        bf16x4 pw = {f2bf(pe[kt * 4]), f2bf(pe[kt * 4 + 1]), f2bf(pe[kt * 4 + 2]), f2bf(pe[kt * 4 + 3])};
        *(bf16x4*)&pbuf[w][l15 * 72 + kt * 16 + quad * 4] = pw;
      }
      // same-wave LDS round-trip: lgkmcnt ordering only, no barrier
      bf16x8 pb0 = *(const bf16x8*)&pbuf[w][l15 * 72 + quad * 8];
      bf16x8 pb1 = *(const bf16x8*)&pbuf[w][l15 * 72 + 32 + quad * 8];
#pragma unroll
      for (int dt = 0; dt < 4; ++dt) {
        oacc[dt] = __builtin_amdgcn_mfma_f32_16x16x32_bf16(vf[dt][0], pb0, oacc[dt], 0, 0, 0);
        oacc[dt] = __builtin_amdgcn_mfma_f32_16x16x32_bf16(vf[dt][1], pb1, oacc[dt], 0, 0, 0);
      }
    }
    __syncthreads();  // all reads of Ks/Vs done
    if (pf) {  // write prefetched tile t+1 into LDS (vmcnt drained by compiler)
      bf16* kd = &Ks[(w * 16) * 64] + lane * 8;
      *(bf16x8*)kd = rk0;
      *(bf16x8*)(kd + 512) = rk1;
      bf16* vd = &Vs[(w * 16) * 64] + lane * 8;
      *(bf16x8*)vd = rv0;
      *(bf16x8*)(vd + 512) = rv1;
    }
    __syncthreads();  // writes visible before next tile's reads
  }
  float lrun = lpart;
  lrun += __shfl_xor(lrun, 16);
  lrun += __shfl_xor(lrun, 32);
  int b0 = bh >> 4, h = bh & 15;
  float inv = 1.f / lrun;
  int q = qmin_w + l15;
  bf16* obase = Ob + ((size_t)(b0 * 2048 + q)) * 1024 + h * 64;
#pragma unroll
  for (int dt = 0; dt < 4; ++dt)
#pragma unroll
    for (int r = 0; r < 4; ++r)
      obase[dt * 16 + quad * 4 + r] = f2bf(oacc[dt][r] * inv);
}

// ---------------- output projection GEMM ------------------------------------
// R17: ported R16's dbuf single-barrier pipeline (BK=32, stage(t+1) issued
// before compute(t), 2x12KB LDS, same verified 2-bit XOR swizzle). The R15
// version paid a full vmcnt(0) drain per k-step with nothing in flight.
__global__ __launch_bounds__(256) void gemm_out_kernel(
    const bf16* __restrict__ Ob, const bf16* __restrict__ wob,
    float* __restrict__ out) {
  __shared__ __align__(16) bf16 smem[12288];  // {A[4096]|B[2048]} x2
  int tid = threadIdx.x;
  int lane = tid & 63, w = tid >> 6;
  int l15 = lane & 15, quad = lane >> 4;
  int bid = blockIdx.x;
  int xcd = bid & 7, j = bid >> 3;       // j in [0,64)
  int by = (xcd & 3) * 8 + (j & 7);      // 32 M-tiles
  int bx = (xcd >> 2) * 8 + (j >> 3);    // 16 N-tiles
  int mb = by * 128, nb = bx * 64;
  int mq = (w & 1) * 64, nq = (w >> 1) * 32;
  int rq = lane >> 2;
  int gsrc = (lane & 3) ^ (rq & 3) ^ (lane >> 4);
  const bf16* agp0 = Ob + (size_t)(mb + w * 32 + rq) * 1024 + gsrc * 8;
  const bf16* agp1 = agp0 + 16 * 1024;
  const bf16* bgp0 = wob + (size_t)(nb + w * 16 + rq) * 1024 + gsrc * 8;
  f32x4 acc[4][2];
#pragma unroll
  for (int i = 0; i < 4; ++i)
#pragma unroll
    for (int j2 = 0; j2 < 2; ++j2)
      for (int r = 0; r < 4; ++r) acc[i][j2][r] = 0.f;
  // prologue: stage k-step 0 into buffer 0
  gl_lds16(agp0, smem + w * 1024);
  gl_lds16(agp1, smem + w * 1024 + 512);
  gl_lds16(bgp0, smem + 4096 + w * 512);
  agp0 += 32; agp1 += 32; bgp0 += 32;
  __syncthreads();
  int rg = quad ^ (l15 & 3) ^ (l15 >> 2);
  for (int kt = 0; kt < 32; ++kt) {
    bf16* Ab = smem + (kt & 1) * 6144;
    bf16* Bb = Ab + 4096;
    if (kt < 31) {  // stage k-step kt+1 into the other buffer (overlaps MFMA)
      bf16* An = smem + ((kt & 1) ^ 1) * 6144;
      gl_lds16(agp0, An + w * 1024);
      gl_lds16(agp1, An + w * 1024 + 512);
      gl_lds16(bgp0, An + 4096 + w * 512);
      agp0 += 32; agp1 += 32; bgp0 += 32;
    }
    bf16x8 af[4], bfr[2];
#pragma unroll
    for (int mt = 0; mt < 4; ++mt)
      af[mt] = *(const bf16x8*)(Ab + (mq + mt * 16 + l15) * 32 + rg * 8);
#pragma unroll
    for (int nt = 0; nt < 2; ++nt)
      bfr[nt] = *(const bf16x8*)(Bb + (nq + nt * 16 + l15) * 32 + rg * 8);
#pragma unroll
    for (int mt = 0; mt < 4; ++mt)
#pragma unroll
      for (int nt = 0; nt < 2; ++nt)
        acc[mt][nt] = __builtin_amdgcn_mfma_f32_16x16x32_bf16(af[mt], bfr[nt], acc[mt][nt], 0, 0, 0);
    __syncthreads();
  }
#pragma unroll
  for (int mt = 0; mt < 4; ++mt)
#pragma unroll
    for (int nt = 0; nt < 2; ++nt)
#pragma unroll
      for (int r = 0; r < 4; ++r)
        out[(size_t)(mb + mq + mt * 16 + quad * 4 + r) * 1024 + nb + nq + nt * 16 + l15] = acc[mt][nt][r];
}

extern "C" void kernel_launch(void* const* d_in, const int* in_sizes, int n_in,
                              void* d_out, int out_size, void* d_ws, size_t ws_size,
                              hipStream_t stream) {
  const float* x  = (const float*)d_in[0];
  const float* wq = (const float*)d_in[1];
  const float* wk = (const float*)d_in[2];
  const float* wv = (const float*)d_in[3];
  const float* wo = (const float*)d_in[4];
  const int* pos  = (const int*)d_in[5];
  float* out = (float*)d_out;
  // ws layout (bf16 elems): xb[4M] | wb[4x1M] | Q[4M] | K[4M] | Vt[4M] | O[4M]
  bf16* wsb = (bf16*)d_ws;
  bf16* xb  = wsb;
  bf16* wb  = wsb + 4194304;
  bf16* Qb  = wsb + 8388608;
  bf16* Kb  = wsb + 12582912;
  bf16* Vtb = wsb + 16777216;
  bf16* Obf = wsb + 20971520;
  float* tab = (float*)Obf;  // 512 KB table, dead before attn writes Obf
  hipLaunchKernelGGL(cvt_kernel, dim3(8448), dim3(256), 0, stream, x, wq, wk, wv, wo, wsb, pos, tab);
  hipLaunchKernelGGL(gemm_qkv_kernel, dim3(768), dim3(256), 0, stream, xb, wb, tab, Qb, Kb, Vtb);
  hipLaunchKernelGGL(attn_kernel, dim3(1024), dim3(256), 0, stream, Qb, Kb, Vtb, Obf);
  hipLaunchKernelGGL(gemm_out_kernel, dim3(512), dim3(256), 0, stream, Obf, wb + 3 * 1048576, out);
}